// Round 2
// baseline (243.021 us; speedup 1.0000x reference)
//
#include <hip/hip_runtime.h>
#include <hip/hip_bf16.h>
#include <math.h>

#define DT (1.0f / 60.0f)

typedef __bf16 bf16x8 __attribute__((ext_vector_type(8)));
typedef float f32x4 __attribute__((ext_vector_type(4)));

#define XSTRIDE 832   // 416 bf16 cols (layer-1 input slab in LDS)
#define HSTRIDE 1040  // 512 bf16 cols padded +8 elems: breaks 1024B bank alias

__device__ __forceinline__ void async_copy16(void* lds, const void* g) {
    __builtin_amdgcn_global_load_lds(
        (__attribute__((address_space(1))) void*)(g),
        (__attribute__((address_space(3))) void*)(lds),
        16, 0, 0);
}

// ---------------------------------------------------------------------------
// Weight prep: W (K x N fp32, row-major) -> Wt (N x Kpad bf16, k-contiguous)
// ---------------------------------------------------------------------------
__global__ void prep_weights(const float* __restrict__ W1,
                             const float* __restrict__ W2,
                             const float* __restrict__ W3,
                             __hip_bfloat16* __restrict__ W1t,
                             __hip_bfloat16* __restrict__ W2t,
                             __hip_bfloat16* __restrict__ W3t) {
    int b = blockIdx.x;
    int tid = threadIdx.x;
    if (b < 512) {
        int n = b;  // W1: 414x512 -> W1t: 512x416 (k 414..415 zero)
        for (int k = tid; k < 416; k += 128)
            W1t[n * 416 + k] = __float2bfloat16(k < 414 ? W1[k * 512 + n] : 0.0f);
    } else if (b < 1024) {
        int n = b - 512;  // W2: 512x512 -> W2t: 512x512
        for (int k = tid; k < 512; k += 128)
            W2t[n * 512 + k] = __float2bfloat16(W2[k * 512 + n]);
    } else {
        int n = b - 1024;  // W3: 512x120 -> W3t: 128x512 (rows 120..127 zero)
        for (int k = tid; k < 512; k += 128)
            W3t[n * 512 + k] = __float2bfloat16(n < 120 ? W3[k * 120 + n] : 0.0f);
    }
}

// ---------------------------------------------------------------------------
// Build x (B x 416 bf16): [0:300) obs, [300:414) quat 6d feats, [414:416) pad.
// 256 threads = 2 rows per block.
// ---------------------------------------------------------------------------
__global__ __launch_bounds__(256) void build_x(const float* __restrict__ obs,
                                               const float* __restrict__ action,
                                               __hip_bfloat16* __restrict__ x) {
    int row = blockIdx.x * 2 + (threadIdx.x >> 7);
    int tid = threadIdx.x & 127;
    const float* o = obs + (size_t)row * 300;
    __hip_bfloat16* xr = x + (size_t)row * 416;
    for (int c = tid; c < 300; c += 128)
        xr[c] = __float2bfloat16(o[c]);
    if (tid < 19) {
        const float* a = action + (size_t)row * 57 + tid * 3;
        float rx = a[0], ry = a[1], rz = a[2];
        float ang = sqrtf(rx * rx + ry * ry + rz * rz);
        float half = 0.5f * ang;
        float s;
        if (ang < 1e-8f)
            s = 0.5f - ang * ang * (1.0f / 48.0f);
        else
            s = sinf(half) / ang;
        float qx = rx * s, qy = ry * s, qz = rz * s, qw = cosf(half);
        // flip_quat_by_w dropped: R(-q) == R(q), vec6d is quadratic in q.
        float r00 = 1.0f - 2.0f * (qy * qy + qz * qz);
        float r10 = 2.0f * (qx * qy + qz * qw);
        float r20 = 2.0f * (qx * qz - qy * qw);
        float r01 = 2.0f * (qx * qy - qz * qw);
        float r11 = 1.0f - 2.0f * (qx * qx + qz * qz);
        float r21 = 2.0f * (qy * qz + qx * qw);
        __hip_bfloat16* p = xr + 300 + tid * 6;
        p[0] = __float2bfloat16(r00);
        p[1] = __float2bfloat16(r01);
        p[2] = __float2bfloat16(r10);
        p[3] = __float2bfloat16(r11);
        p[4] = __float2bfloat16(r20);
        p[5] = __float2bfloat16(r21);
    } else if (tid == 19) {
        xr[414] = __float2bfloat16(0.0f);
        xr[415] = __float2bfloat16(0.0f);
    }
}

// ---------------------------------------------------------------------------
// Fused MLP + integrate. 256 blocks x 512 threads (8 waves, 2/SIMD).
// Block = 128 batch rows. Wave (wm,wn) computes 64x128 of the 128x512 layer
// output as 4i x 8j grid of 16x16x32 bf16 MFMAs. A-frags from LDS,
// B-frags (weights) per-lane from global (L2-resident). No barriers inside
// K-loops.
// ---------------------------------------------------------------------------
template <int K, int KSTEPS, int ASTRIDE>
__device__ __forceinline__ void mlp_layer(const char* Abase,
                                          const __hip_bfloat16* __restrict__ Bbase,
                                          f32x4 (&acc)[4][8]) {
#pragma unroll 2
    for (int ks = 0; ks < KSTEPS; ks++) {
        const char* ap = Abase + ks * 64;
        const __hip_bfloat16* bp = Bbase + ks * 32;
        bf16x8 af[4], bfv[4];
#pragma unroll
        for (int i = 0; i < 4; i++)
            af[i] = *(const bf16x8*)(ap + i * 16 * ASTRIDE);
#pragma unroll
        for (int j = 0; j < 4; j++)
            bfv[j] = *(const bf16x8*)(bp + j * 16 * K);
#pragma unroll
        for (int i = 0; i < 4; i++)
#pragma unroll
            for (int j = 0; j < 4; j++)
                acc[i][j] = __builtin_amdgcn_mfma_f32_16x16x32_bf16(
                    af[i], bfv[j], acc[i][j], 0, 0, 0);
#pragma unroll
        for (int j = 0; j < 4; j++)
            bfv[j] = *(const bf16x8*)(bp + (j + 4) * 16 * K);
#pragma unroll
        for (int i = 0; i < 4; i++)
#pragma unroll
            for (int j = 0; j < 4; j++)
                acc[i][j + 4] = __builtin_amdgcn_mfma_f32_16x16x32_bf16(
                    af[i], bfv[j], acc[i][j + 4], 0, 0, 0);
    }
}

__device__ __forceinline__ void store_h_relu(const f32x4 (&acc)[4][8],
                                             char* smem, const float* bias,
                                             int wm, int wn, int lrow,
                                             int kgrp) {
#pragma unroll
    for (int j = 0; j < 8; j++) {
        int col = wn * 128 + j * 16 + lrow;
        float bb = bias[col];
#pragma unroll
        for (int i = 0; i < 4; i++) {
            char* p = smem + (wm * 64 + i * 16 + kgrp * 4) * HSTRIDE + col * 2;
#pragma unroll
            for (int r = 0; r < 4; r++) {
                float v = acc[i][j][r] + bb;
                v = v > 0.0f ? v : 0.0f;
                *(__hip_bfloat16*)(p + r * HSTRIDE) = __float2bfloat16(v);
            }
        }
    }
}

__device__ __forceinline__ void quat_apply3(float qx, float qy, float qz,
                                            float qw, float vx, float vy,
                                            float vz, float& ox, float& oy,
                                            float& oz) {
    float tx = 2.0f * (qy * vz - qz * vy);
    float ty = 2.0f * (qz * vx - qx * vz);
    float tz = 2.0f * (qx * vy - qy * vx);
    ox = vx + qw * tx + (qy * tz - qz * ty);
    oy = vy + qw * ty + (qz * tx - qx * tz);
    oz = vz + qw * tz + (qx * ty - qy * tx);
}

__global__ __launch_bounds__(512, 2) void fused_mlp(
    const __hip_bfloat16* __restrict__ x, const __hip_bfloat16* __restrict__ W1t,
    const float* __restrict__ b1, const __hip_bfloat16* __restrict__ W2t,
    const float* __restrict__ b2, const __hip_bfloat16* __restrict__ W3t,
    const float* __restrict__ b3, const float* __restrict__ dstd,
    const float* __restrict__ dmean, const float* __restrict__ state,
    float* __restrict__ out) {
    alignas(16) __shared__ char smem[128 * HSTRIDE];  // 133120 B
    const int tid = threadIdx.x;
    const int blk = blockIdx.x;
    const int lane = tid & 63, w = tid >> 6;
    const int wm = w >> 2, wn = w & 3;
    const int lrow = lane & 15, kgrp = lane >> 4;

    // ---- stage x slab: 128 rows x 416 bf16 = 106496 B, contiguous ----
    {
        const char* xg = (const char*)(x + (size_t)blk * 128 * 416) + tid * 16;
        char* xl = smem + tid * 16;
#pragma unroll
        for (int i = 0; i < 13; i++)
            async_copy16(xl + i * 8192, xg + i * 8192);
    }
    __syncthreads();  // drains vmcnt: x-LDS ready

    f32x4 acc[4][8];
    f32x4 zero4 = {0.0f, 0.0f, 0.0f, 0.0f};
#pragma unroll
    for (int i = 0; i < 4; i++)
#pragma unroll
        for (int j = 0; j < 8; j++) acc[i][j] = zero4;

    // ---- layer 1: h1 = relu(x @ W1 + b1), K=416 ----
    mlp_layer<416, 13, XSTRIDE>(
        smem + (wm * 64 + lrow) * XSTRIDE + kgrp * 16,
        W1t + (wn * 128 + lrow) * 416 + kgrp * 8, acc);
    __syncthreads();  // all waves done reading x
    store_h_relu(acc, smem, b1, wm, wn, lrow, kgrp);
    __syncthreads();  // h1 visible

    // ---- layer 2: h2 = relu(h1 @ W2 + b2), K=512 ----
#pragma unroll
    for (int i = 0; i < 4; i++)
#pragma unroll
        for (int j = 0; j < 8; j++) acc[i][j] = zero4;
    mlp_layer<512, 16, HSTRIDE>(
        smem + (wm * 64 + lrow) * HSTRIDE + kgrp * 16,
        W2t + (wn * 128 + lrow) * 512 + kgrp * 8, acc);
    __syncthreads();  // all waves done reading h1
    store_h_relu(acc, smem, b2, wm, wn, lrow, kgrp);
    __syncthreads();  // h2 visible

    // ---- layer 3: delta = (h2 @ W3 + b3) * std + mean, N=120(128) ----
    // remap: wave w computes rows [w*16, +16) x cols [0,128) as 1x8 tiles
    f32x4 a3[8];
#pragma unroll
    for (int j = 0; j < 8; j++) a3[j] = zero4;
    {
        const char* Ab = smem + (w * 16 + lrow) * HSTRIDE + kgrp * 16;
        const __hip_bfloat16* Bb = W3t + lrow * 512 + kgrp * 8;
#pragma unroll 2
        for (int ks = 0; ks < 16; ks++) {
            bf16x8 a = *(const bf16x8*)(Ab + ks * 64);
#pragma unroll
            for (int j = 0; j < 8; j++) {
                bf16x8 bb = *(const bf16x8*)(Bb + j * 16 * 512 + ks * 32);
                a3[j] = __builtin_amdgcn_mfma_f32_16x16x32_bf16(a, bb, a3[j],
                                                                0, 0, 0);
            }
        }
    }
    __syncthreads();  // all waves done reading h2; smem now free for delta

    // delta -> LDS fp32 [128 x 120]
    float* dl = (float*)smem;
#pragma unroll
    for (int j = 0; j < 8; j++) {
        int col = j * 16 + lrow;
        if (col < 120) {
            float bb = b3[col], sc = dstd[col], mn = dmean[col];
#pragma unroll
            for (int r = 0; r < 4; r++) {
                int row = w * 16 + kgrp * 4 + r;
                dl[row * 120 + col] = (a3[j][r] + bb) * sc + mn;
            }
        }
    }
    __syncthreads();

    // ---- integrate: 128 rows x 20 bodies = 2560 items, 5 per thread ----
#pragma unroll
    for (int it = 0; it < 5; it++) {
        int idx = tid + it * 512;
        int lr = idx / 20;
        int body = idx - lr * 20;
        int rowg = blk * 128 + lr;
        const float* sb = state + (size_t)rowg * 260 + body * 13;
        const float* rq = state + (size_t)rowg * 260 + 3;  // root quat
        float qx = rq[0], qy = rq[1], qz = rq[2], qw = rq[3];
        const float* d = dl + lr * 120 + body * 6;

        float lx, ly, lz, ax, ay, az;
        quat_apply3(qx, qy, qz, qw, d[0], d[1], d[2], lx, ly, lz);
        quat_apply3(qx, qy, qz, qw, d[3], d[4], d[5], ax, ay, az);

        float vx = sb[7] + lx, vy = sb[8] + ly, vz = sb[9] + lz;
        float wx = sb[10] + ax, wy = sb[11] + ay, wz = sb[12] + az;
        float px = sb[0] + vx * DT, py = sb[1] + vy * DT, pz = sb[2] + vz * DT;

        float rx = sb[3], ry = sb[4], rz = sb[5], rw = sb[6];
        float dqx = rw * wx + (wy * rz - wz * ry);
        float dqy = rw * wy + (wz * rx - wx * rz);
        float dqz = rw * wz + (wx * ry - wy * rx);
        float dqw = -(wx * rx + wy * ry + wz * rz);
        float h = 0.5f * DT;
        float nx = rx + h * dqx, ny = ry + h * dqy, nz = rz + h * dqz,
              nw = rw + h * dqw;
        float inv = 1.0f / sqrtf(nx * nx + ny * ny + nz * nz + nw * nw);

        float* o = out + (size_t)rowg * 260 + body * 13;
        o[0] = px;
        o[1] = py;
        o[2] = pz;
        o[3] = nx * inv;
        o[4] = ny * inv;
        o[5] = nz * inv;
        o[6] = nw * inv;
        o[7] = vx;
        o[8] = vy;
        o[9] = vz;
        o[10] = wx;
        o[11] = wy;
        o[12] = wz;
    }
}

// ---------------------------------------------------------------------------
extern "C" void kernel_launch(void* const* d_in, const int* in_sizes, int n_in,
                              void* d_out, int out_size, void* d_ws,
                              size_t ws_size, hipStream_t stream) {
    const float* state = (const float*)d_in[0];
    const float* action = (const float*)d_in[1];
    const float* obs = (const float*)d_in[2];
    const float* W1 = (const float*)d_in[3];
    const float* b1 = (const float*)d_in[4];
    const float* W2 = (const float*)d_in[5];
    const float* b2 = (const float*)d_in[6];
    const float* W3 = (const float*)d_in[7];
    const float* b3 = (const float*)d_in[8];
    const float* dmean = (const float*)d_in[9];
    const float* dstd = (const float*)d_in[10];
    float* out = (float*)d_out;
    char* ws = (char*)d_ws;

    const int B = in_sizes[1] / 57;  // 32768

    __hip_bfloat16* W1t = (__hip_bfloat16*)(ws);           // 512x416
    __hip_bfloat16* W2t = (__hip_bfloat16*)(ws + 425984);  // 512x512
    __hip_bfloat16* W3t = (__hip_bfloat16*)(ws + 950272);  // 128x512
    __hip_bfloat16* x = (__hip_bfloat16*)(ws + 1081344);   // B x 416

    prep_weights<<<1152, 128, 0, stream>>>(W1, W2, W3, W1t, W2t, W3t);
    build_x<<<B / 2, 256, 0, stream>>>(obs, action, x);
    fused_mlp<<<B / 128, 512, 0, stream>>>(x, W1t, b1, W2t, b2, W3t, b3, dstd,
                                           dmean, state, out);
}

// Round 3
// 179.047 us; speedup vs baseline: 1.3573x; 1.3573x over previous
//
#include <hip/hip_runtime.h>
#include <hip/hip_bf16.h>
#include <math.h>

#define DT (1.0f / 60.0f)

typedef __bf16 bf16x8 __attribute__((ext_vector_type(8)));
typedef float f32x4 __attribute__((ext_vector_type(4)));

#define XSTRIDE 848   // 424 bf16 cols: 212 dwords % 8 == 4 -> 2-way (free)
#define HSTRIDE 1040  // 520 bf16 cols: 260 dwords % 8 == 4 -> 2-way (free)

// ---------------------------------------------------------------------------
// Weight prep into MFMA-fragment-packed layout.
// Packed: frag(ks, nt) is 1KB contiguous; lane l (lrow=l&15, kgrp=l>>4) reads
// bytes [l*16, l*16+16) = W[k = ks*32 + kgrp*8 + e][n = nt*16 + lrow], e=0..7.
// So every B-load in the GEMM is wave-uniform-base + lane*16 (coalesced).
// ---------------------------------------------------------------------------
__global__ __launch_bounds__(256) void prep_weights(
    const float* __restrict__ W1, const float* __restrict__ W2,
    const float* __restrict__ W3, __hip_bfloat16* __restrict__ W1p,
    __hip_bfloat16* __restrict__ W2p, __hip_bfloat16* __restrict__ W3p) {
    int idx = blockIdx.x * 256 + threadIdx.x;
    // W1p: KS=13, NT=32 (K=416 pad of 414, N=512): 212992 elems
    if (idx < 212992) {
        int d = idx;
        int e = d & 7, l = (d >> 3) & 63, t = d >> 9;
        int nt = t & 31, ks = t >> 5;
        int n = nt * 16 + (l & 15);
        int k = ks * 32 + (l >> 4) * 8 + e;
        W1p[d] = __float2bfloat16(k < 414 ? W1[k * 512 + n] : 0.0f);
        return;
    }
    idx -= 212992;
    // W2p: KS=16, NT=32: 262144 elems
    if (idx < 262144) {
        int d = idx;
        int e = d & 7, l = (d >> 3) & 63, t = d >> 9;
        int nt = t & 31, ks = t >> 5;
        int n = nt * 16 + (l & 15);
        int k = ks * 32 + (l >> 4) * 8 + e;
        W2p[d] = __float2bfloat16(W2[k * 512 + n]);
        return;
    }
    idx -= 262144;
    // W3p: KS=16, NT=8 (N=128 pad of 120): 65536 elems
    if (idx < 65536) {
        int d = idx;
        int e = d & 7, l = (d >> 3) & 63, t = d >> 9;
        int nt = t & 7, ks = t >> 3;
        int n = nt * 16 + (l & 15);
        int k = ks * 32 + (l >> 4) * 8 + e;
        W3p[d] = __float2bfloat16(n < 120 ? W3[k * 120 + n] : 0.0f);
    }
}

// ---------------------------------------------------------------------------
// K-loop: A-frags from LDS, packed-B frags from global (coalesced), explicit
// double-buffered B prefetch. acc(4 m-tiles x 8 n-tiles of 16x16).
// ---------------------------------------------------------------------------
template <int KSTEPS, int NT, int ASTRIDE>
__device__ __forceinline__ void mlp_layer(const char* Abase, const char* Bbase,
                                          int laneOff, f32x4 (&acc)[4][8]) {
    bf16x8 b0[8], b1[8];
#pragma unroll
    for (int j = 0; j < 8; j++)
        b0[j] = *(const bf16x8*)(Bbase + (j << 10) + laneOff);
#pragma unroll
    for (int ks = 0; ks < KSTEPS; ks++) {
        if (ks + 1 < KSTEPS) {
            if ((ks & 1) == 0) {
#pragma unroll
                for (int j = 0; j < 8; j++)
                    b1[j] = *(const bf16x8*)(Bbase + (((ks + 1) * NT + j) << 10) + laneOff);
            } else {
#pragma unroll
                for (int j = 0; j < 8; j++)
                    b0[j] = *(const bf16x8*)(Bbase + (((ks + 1) * NT + j) << 10) + laneOff);
            }
        }
        bf16x8 af[4];
#pragma unroll
        for (int i = 0; i < 4; i++)
            af[i] = *(const bf16x8*)(Abase + ks * 64 + i * 16 * ASTRIDE);
#pragma unroll
        for (int i = 0; i < 4; i++)
#pragma unroll
            for (int j = 0; j < 8; j++)
                acc[i][j] = __builtin_amdgcn_mfma_f32_16x16x32_bf16(
                    af[i], (ks & 1) ? b1[j] : b0[j], acc[i][j], 0, 0, 0);
    }
}

__device__ __forceinline__ void store_h_relu(const f32x4 (&acc)[4][8],
                                             char* smem, const float* bias,
                                             int wm, int wn, int lrow,
                                             int kgrp) {
#pragma unroll
    for (int j = 0; j < 8; j++) {
        int col = wn * 128 + j * 16 + lrow;
        float bb = bias[col];
#pragma unroll
        for (int i = 0; i < 4; i++) {
            char* p = smem + (wm * 64 + i * 16 + kgrp * 4) * HSTRIDE + col * 2;
#pragma unroll
            for (int r = 0; r < 4; r++) {
                float v = acc[i][j][r] + bb;
                v = v > 0.0f ? v : 0.0f;
                *(__hip_bfloat16*)(p + r * HSTRIDE) = __float2bfloat16(v);
            }
        }
    }
}

__device__ __forceinline__ void quat_apply3(float qx, float qy, float qz,
                                            float qw, float vx, float vy,
                                            float vz, float& ox, float& oy,
                                            float& oz) {
    float tx = 2.0f * (qy * vz - qz * vy);
    float ty = 2.0f * (qz * vx - qx * vz);
    float tz = 2.0f * (qx * vy - qy * vx);
    ox = vx + qw * tx + (qy * tz - qz * ty);
    oy = vy + qw * ty + (qz * tx - qx * tz);
    oz = vz + qw * tz + (qx * ty - qy * tx);
}

// ---------------------------------------------------------------------------
// Fused: build features + 3-layer MLP + integrate. 256 blocks x 512 threads.
// Block = 128 batch rows resident in LDS the whole time.
// ---------------------------------------------------------------------------
__global__ __launch_bounds__(512, 2) void fused_mlp(
    const float* __restrict__ obs, const float* __restrict__ action,
    const __hip_bfloat16* __restrict__ W1p, const float* __restrict__ b1,
    const __hip_bfloat16* __restrict__ W2p, const float* __restrict__ b2,
    const __hip_bfloat16* __restrict__ W3p, const float* __restrict__ b3,
    const float* __restrict__ dstd, const float* __restrict__ dmean,
    const float* __restrict__ state, float* __restrict__ out) {
    alignas(16) __shared__ char smem[128 * HSTRIDE];  // 133120 B
    const int tid = threadIdx.x;
    const int blk = blockIdx.x;
    const int lane = tid & 63, w = tid >> 6;
    const int wm = w >> 2, wn = w & 3;
    const int lrow = lane & 15, kgrp = lane >> 4;
    const int laneOff = lane * 16;

    // ---- stage obs -> bf16 LDS (row stride XSTRIDE), fused feature build ---
    {
        const float4* og = (const float4*)obs + (size_t)blk * 128 * 75;
#pragma unroll
        for (int i = 0; i < 19; i++) {
            int f = tid + i * 512;
            if (f < 9600) {
                int row = f / 75;
                int c4 = f - row * 75;
                float4 v = og[f];
                union { __hip_bfloat16 h[4]; uint2 u; } pk;
                pk.h[0] = __float2bfloat16(v.x);
                pk.h[1] = __float2bfloat16(v.y);
                pk.h[2] = __float2bfloat16(v.z);
                pk.h[3] = __float2bfloat16(v.w);
                *(uint2*)(smem + row * XSTRIDE + c4 * 8) = pk.u;
            }
        }
        // quat 6d features: 128 rows x 19 quats
#pragma unroll
        for (int i = 0; i < 5; i++) {
            int q = tid + i * 512;
            if (q < 2432) {
                int row = q / 19;
                int j = q - row * 19;
                const float* a = action + ((size_t)(blk * 128 + row)) * 57 + j * 3;
                float rx = a[0], ry = a[1], rz = a[2];
                float ang = sqrtf(rx * rx + ry * ry + rz * rz);
                float half = 0.5f * ang;
                float s;
                if (ang < 1e-8f)
                    s = 0.5f - ang * ang * (1.0f / 48.0f);
                else
                    s = sinf(half) / ang;
                float qx = rx * s, qy = ry * s, qz = rz * s, qw = cosf(half);
                // flip_quat_by_w dropped: R(-q) == R(q).
                union { __hip_bfloat16 h[6]; uint u[3]; } pq;
                pq.h[0] = __float2bfloat16(1.0f - 2.0f * (qy * qy + qz * qz));
                pq.h[1] = __float2bfloat16(2.0f * (qx * qy - qz * qw));
                pq.h[2] = __float2bfloat16(2.0f * (qx * qy + qz * qw));
                pq.h[3] = __float2bfloat16(1.0f - 2.0f * (qx * qx + qz * qz));
                pq.h[4] = __float2bfloat16(2.0f * (qx * qz - qy * qw));
                pq.h[5] = __float2bfloat16(2.0f * (qy * qz + qx * qw));
                char* p = smem + row * XSTRIDE + 600 + j * 12;
                *(uint*)p = pq.u[0];
                *(uint*)(p + 4) = pq.u[1];
                *(uint*)(p + 8) = pq.u[2];
            }
        }
        // zero pad cols 414..423 (bytes 828..847)
#pragma unroll
        for (int i = 0; i < 2; i++) {
            int id = tid + i * 512;
            if (id < 640) {
                int row = id / 5;
                int p = id - row * 5;
                *(uint*)(smem + row * XSTRIDE + 828 + p * 4) = 0u;
            }
        }
    }
    __syncthreads();  // x slab ready

    f32x4 acc[4][8];
    f32x4 zero4 = {0.0f, 0.0f, 0.0f, 0.0f};
#pragma unroll
    for (int i = 0; i < 4; i++)
#pragma unroll
        for (int j = 0; j < 8; j++) acc[i][j] = zero4;

    // ---- layer 1: h1 = relu(x @ W1 + b1), K=416 ----
    mlp_layer<13, 32, XSTRIDE>(smem + (wm * 64 + lrow) * XSTRIDE + kgrp * 16,
                               (const char*)W1p + (wn << 13), laneOff, acc);
    __syncthreads();
    store_h_relu(acc, smem, b1, wm, wn, lrow, kgrp);
    __syncthreads();

    // ---- layer 2: h2 = relu(h1 @ W2 + b2), K=512 ----
#pragma unroll
    for (int i = 0; i < 4; i++)
#pragma unroll
        for (int j = 0; j < 8; j++) acc[i][j] = zero4;
    mlp_layer<16, 32, HSTRIDE>(smem + (wm * 64 + lrow) * HSTRIDE + kgrp * 16,
                               (const char*)W2p + (wn << 13), laneOff, acc);
    __syncthreads();
    store_h_relu(acc, smem, b2, wm, wn, lrow, kgrp);
    __syncthreads();

    // ---- layer 3: delta = (h2 @ W3 + b3) * std + mean, N=120(128) ----
    // wave w computes rows [w*16, +16) x all 128 cols (8 n-tiles)
    f32x4 a3[8];
#pragma unroll
    for (int j = 0; j < 8; j++) a3[j] = zero4;
    {
        const char* Ab = smem + (w * 16 + lrow) * HSTRIDE + kgrp * 16;
        const char* Bb = (const char*)W3p;
        bf16x8 c0[8], c1[8];
#pragma unroll
        for (int j = 0; j < 8; j++)
            c0[j] = *(const bf16x8*)(Bb + (j << 10) + laneOff);
#pragma unroll
        for (int ks = 0; ks < 16; ks++) {
            if (ks + 1 < 16) {
                if ((ks & 1) == 0) {
#pragma unroll
                    for (int j = 0; j < 8; j++)
                        c1[j] = *(const bf16x8*)(Bb + (((ks + 1) * 8 + j) << 10) + laneOff);
                } else {
#pragma unroll
                    for (int j = 0; j < 8; j++)
                        c0[j] = *(const bf16x8*)(Bb + (((ks + 1) * 8 + j) << 10) + laneOff);
                }
            }
            bf16x8 a = *(const bf16x8*)(Ab + ks * 64);
#pragma unroll
            for (int j = 0; j < 8; j++)
                a3[j] = __builtin_amdgcn_mfma_f32_16x16x32_bf16(
                    a, (ks & 1) ? c1[j] : c0[j], a3[j], 0, 0, 0);
        }
    }
    __syncthreads();  // all waves done reading h2; smem free for delta

    // delta -> LDS fp32 [128 x 120]
    float* dl = (float*)smem;
#pragma unroll
    for (int j = 0; j < 8; j++) {
        int col = j * 16 + lrow;
        if (col < 120) {
            float bb = b3[col], sc = dstd[col], mn = dmean[col];
#pragma unroll
            for (int r = 0; r < 4; r++) {
                int row = w * 16 + kgrp * 4 + r;
                dl[row * 120 + col] = (a3[j][r] + bb) * sc + mn;
            }
        }
    }
    __syncthreads();

    // ---- integrate: 128 rows x 20 bodies = 2560 items, 5 per thread ----
#pragma unroll
    for (int it = 0; it < 5; it++) {
        int idx = tid + it * 512;
        int lr = idx / 20;
        int body = idx - lr * 20;
        int rowg = blk * 128 + lr;
        const float* sb = state + (size_t)rowg * 260 + body * 13;
        const float* rq = state + (size_t)rowg * 260 + 3;  // root quat
        float qx = rq[0], qy = rq[1], qz = rq[2], qw = rq[3];
        const float* d = dl + lr * 120 + body * 6;

        float lx, ly, lz, ax, ay, az;
        quat_apply3(qx, qy, qz, qw, d[0], d[1], d[2], lx, ly, lz);
        quat_apply3(qx, qy, qz, qw, d[3], d[4], d[5], ax, ay, az);

        float vx = sb[7] + lx, vy = sb[8] + ly, vz = sb[9] + lz;
        float wx = sb[10] + ax, wy = sb[11] + ay, wz = sb[12] + az;
        float px = sb[0] + vx * DT, py = sb[1] + vy * DT, pz = sb[2] + vz * DT;

        float rx = sb[3], ry = sb[4], rz = sb[5], rw = sb[6];
        float dqx = rw * wx + (wy * rz - wz * ry);
        float dqy = rw * wy + (wz * rx - wx * rz);
        float dqz = rw * wz + (wx * ry - wy * rx);
        float dqw = -(wx * rx + wy * ry + wz * rz);
        float h = 0.5f * DT;
        float nx = rx + h * dqx, ny = ry + h * dqy, nz = rz + h * dqz,
              nw = rw + h * dqw;
        float inv = 1.0f / sqrtf(nx * nx + ny * ny + nz * nz + nw * nw);

        float* o = out + (size_t)rowg * 260 + body * 13;
        o[0] = px;
        o[1] = py;
        o[2] = pz;
        o[3] = nx * inv;
        o[4] = ny * inv;
        o[5] = nz * inv;
        o[6] = nw * inv;
        o[7] = vx;
        o[8] = vy;
        o[9] = vz;
        o[10] = wx;
        o[11] = wy;
        o[12] = wz;
    }
}

// ---------------------------------------------------------------------------
extern "C" void kernel_launch(void* const* d_in, const int* in_sizes, int n_in,
                              void* d_out, int out_size, void* d_ws,
                              size_t ws_size, hipStream_t stream) {
    const float* state = (const float*)d_in[0];
    const float* action = (const float*)d_in[1];
    const float* obs = (const float*)d_in[2];
    const float* W1 = (const float*)d_in[3];
    const float* b1 = (const float*)d_in[4];
    const float* W2 = (const float*)d_in[5];
    const float* b2 = (const float*)d_in[6];
    const float* W3 = (const float*)d_in[7];
    const float* b3 = (const float*)d_in[8];
    const float* dmean = (const float*)d_in[9];
    const float* dstd = (const float*)d_in[10];
    float* out = (float*)d_out;
    char* ws = (char*)d_ws;

    const int B = in_sizes[1] / 57;  // 32768

    __hip_bfloat16* W1p = (__hip_bfloat16*)(ws);           // 13*32 frags
    __hip_bfloat16* W2p = (__hip_bfloat16*)(ws + 425984);  // 16*32 frags
    __hip_bfloat16* W3p = (__hip_bfloat16*)(ws + 950272);  // 16*8 frags

    prep_weights<<<2112, 256, 0, stream>>>(W1, W2, W3, W1p, W2p, W3p);
    fused_mlp<<<B / 128, 512, 0, stream>>>(obs, action, W1p, b1, W2p, b2, W3p,
                                           b3, dstd, dmean, state, out);
}

// Round 4
// 167.252 us; speedup vs baseline: 1.4530x; 1.0705x over previous
//
#include <hip/hip_runtime.h>
#include <hip/hip_bf16.h>
#include <math.h>

#define DT (1.0f / 60.0f)

typedef __bf16 bf16x8 __attribute__((ext_vector_type(8)));
typedef float f32x4 __attribute__((ext_vector_type(4)));

#define XSTRIDE 848   // 424 bf16 cols: 212 dwords % 8 == 4 -> 2-way (free)
#define HSTRIDE 1040  // 520 bf16 cols: 260 dwords % 8 == 4 -> 2-way (free)

// ---------------------------------------------------------------------------
// Weight prep into MFMA-fragment-packed layout.
// Packed: frag(ks, nt) is 1KB contiguous; lane l (lrow=l&15, kgrp=l>>4) reads
// bytes [l*16, l*16+16) = W[k = ks*32 + kgrp*8 + e][n = nt*16 + lrow], e=0..7.
// Every B-load in the GEMM is wave-uniform-base + lane*16 (coalesced).
// ---------------------------------------------------------------------------
__global__ __launch_bounds__(256) void prep_weights(
    const float* __restrict__ W1, const float* __restrict__ W2,
    const float* __restrict__ W3, __hip_bfloat16* __restrict__ W1p,
    __hip_bfloat16* __restrict__ W2p, __hip_bfloat16* __restrict__ W3p) {
    int idx = blockIdx.x * 256 + threadIdx.x;
    // W1p: KS=13, NT=32 (K=416 pad of 414, N=512): 212992 elems
    if (idx < 212992) {
        int d = idx;
        int e = d & 7, l = (d >> 3) & 63, t = d >> 9;
        int nt = t & 31, ks = t >> 5;
        int n = nt * 16 + (l & 15);
        int k = ks * 32 + (l >> 4) * 8 + e;
        W1p[d] = __float2bfloat16(k < 414 ? W1[k * 512 + n] : 0.0f);
        return;
    }
    idx -= 212992;
    // W2p: KS=16, NT=32: 262144 elems
    if (idx < 262144) {
        int d = idx;
        int e = d & 7, l = (d >> 3) & 63, t = d >> 9;
        int nt = t & 31, ks = t >> 5;
        int n = nt * 16 + (l & 15);
        int k = ks * 32 + (l >> 4) * 8 + e;
        W2p[d] = __float2bfloat16(W2[k * 512 + n]);
        return;
    }
    idx -= 262144;
    // W3p: KS=16, NT=8 (N=128 pad of 120): 65536 elems
    if (idx < 65536) {
        int d = idx;
        int e = d & 7, l = (d >> 3) & 63, t = d >> 9;
        int nt = t & 7, ks = t >> 3;
        int n = nt * 16 + (l & 15);
        int k = ks * 32 + (l >> 4) * 8 + e;
        W3p[d] = __float2bfloat16(n < 120 ? W3[k * 120 + n] : 0.0f);
    }
}

// ---------------------------------------------------------------------------
// K-loop: A-frags from LDS, packed-B frags from global (coalesced), explicit
// double-buffered B prefetch. acc = 4 m-tiles x 8 n-tiles of 16x16.
// Wave wn owns cols [wn*128, +128) and ALL 64 rows (no B duplication).
// ---------------------------------------------------------------------------
template <int KSTEPS, int NT, int ASTRIDE>
__device__ __forceinline__ void mlp_layer(const char* Abase, const char* Bbase,
                                          int laneOff, f32x4 (&acc)[4][8]) {
    bf16x8 b0[8], b1[8];
#pragma unroll
    for (int j = 0; j < 8; j++)
        b0[j] = *(const bf16x8*)(Bbase + (j << 10) + laneOff);
#pragma unroll 2
    for (int ks = 0; ks < KSTEPS; ks++) {
        if (ks + 1 < KSTEPS) {
            if ((ks & 1) == 0) {
#pragma unroll
                for (int j = 0; j < 8; j++)
                    b1[j] = *(const bf16x8*)(Bbase + (((ks + 1) * NT + j) << 10) + laneOff);
            } else {
#pragma unroll
                for (int j = 0; j < 8; j++)
                    b0[j] = *(const bf16x8*)(Bbase + (((ks + 1) * NT + j) << 10) + laneOff);
            }
        }
        bf16x8 af[4];
#pragma unroll
        for (int i = 0; i < 4; i++)
            af[i] = *(const bf16x8*)(Abase + ks * 64 + i * 16 * ASTRIDE);
#pragma unroll
        for (int i = 0; i < 4; i++)
#pragma unroll
            for (int j = 0; j < 8; j++)
                acc[i][j] = __builtin_amdgcn_mfma_f32_16x16x32_bf16(
                    af[i], (ks & 1) ? b1[j] : b0[j], acc[i][j], 0, 0, 0);
    }
}

__device__ __forceinline__ void store_h_relu(const f32x4 (&acc)[4][8],
                                             char* smem, const float* bias,
                                             int wn, int lrow, int kgrp) {
#pragma unroll
    for (int j = 0; j < 8; j++) {
        int col = wn * 128 + j * 16 + lrow;
        float bb = bias[col];
#pragma unroll
        for (int i = 0; i < 4; i++) {
            char* p = smem + (i * 16 + kgrp * 4) * HSTRIDE + col * 2;
#pragma unroll
            for (int r = 0; r < 4; r++) {
                float v = acc[i][j][r] + bb;
                v = v > 0.0f ? v : 0.0f;
                *(__hip_bfloat16*)(p + r * HSTRIDE) = __float2bfloat16(v);
            }
        }
    }
}

__device__ __forceinline__ void quat_apply3(float qx, float qy, float qz,
                                            float qw, float vx, float vy,
                                            float vz, float& ox, float& oy,
                                            float& oz) {
    float tx = 2.0f * (qy * vz - qz * vy);
    float ty = 2.0f * (qz * vx - qx * vz);
    float tz = 2.0f * (qx * vy - qy * vx);
    ox = vx + qw * tx + (qy * tz - qz * ty);
    oy = vy + qw * ty + (qz * tx - qx * tz);
    oz = vz + qw * tz + (qx * ty - qy * tx);
}

// ---------------------------------------------------------------------------
// Fused: build features + 3-layer MLP + integrate.
// 512 blocks x 256 threads (4 waves). Block = 64 batch rows in LDS.
// LDS 66560 B -> 2 blocks/CU: independent blocks hide each other's barriers.
// ---------------------------------------------------------------------------
__global__ __launch_bounds__(256, 2) void fused_mlp(
    const float* __restrict__ obs, const float* __restrict__ action,
    const __hip_bfloat16* __restrict__ W1p, const float* __restrict__ b1,
    const __hip_bfloat16* __restrict__ W2p, const float* __restrict__ b2,
    const __hip_bfloat16* __restrict__ W3p, const float* __restrict__ b3,
    const float* __restrict__ dstd, const float* __restrict__ dmean,
    const float* __restrict__ state, float* __restrict__ out) {
    alignas(16) __shared__ char smem[64 * HSTRIDE];  // 66560 B
    const int tid = threadIdx.x;
    const int blk = blockIdx.x;
    const int lane = tid & 63, wn = tid >> 6;
    const int lrow = lane & 15, kgrp = lane >> 4;
    const int laneOff = lane * 16;

    // ---- stage obs -> bf16 LDS (row stride XSTRIDE), fused feature build ---
    {
        const float4* og = (const float4*)obs + (size_t)blk * 64 * 75;
#pragma unroll
        for (int i = 0; i < 19; i++) {
            int f = tid + i * 256;
            if (f < 4800) {
                int row = f / 75;
                int c4 = f - row * 75;
                float4 v = og[f];
                union { __hip_bfloat16 h[4]; uint2 u; } pk;
                pk.h[0] = __float2bfloat16(v.x);
                pk.h[1] = __float2bfloat16(v.y);
                pk.h[2] = __float2bfloat16(v.z);
                pk.h[3] = __float2bfloat16(v.w);
                *(uint2*)(smem + row * XSTRIDE + c4 * 8) = pk.u;
            }
        }
        // quat 6d features: 64 rows x 19 quats
#pragma unroll
        for (int i = 0; i < 5; i++) {
            int q = tid + i * 256;
            if (q < 1216) {
                int row = q / 19;
                int j = q - row * 19;
                const float* a = action + ((size_t)(blk * 64 + row)) * 57 + j * 3;
                float rx = a[0], ry = a[1], rz = a[2];
                float ang = sqrtf(rx * rx + ry * ry + rz * rz);
                float half = 0.5f * ang;
                float s;
                if (ang < 1e-8f)
                    s = 0.5f - ang * ang * (1.0f / 48.0f);
                else
                    s = sinf(half) / ang;
                float qx = rx * s, qy = ry * s, qz = rz * s, qw = cosf(half);
                // flip_quat_by_w dropped: R(-q) == R(q).
                union { __hip_bfloat16 h[6]; uint u[3]; } pq;
                pq.h[0] = __float2bfloat16(1.0f - 2.0f * (qy * qy + qz * qz));
                pq.h[1] = __float2bfloat16(2.0f * (qx * qy - qz * qw));
                pq.h[2] = __float2bfloat16(2.0f * (qx * qy + qz * qw));
                pq.h[3] = __float2bfloat16(1.0f - 2.0f * (qx * qx + qz * qz));
                pq.h[4] = __float2bfloat16(2.0f * (qx * qz - qy * qw));
                pq.h[5] = __float2bfloat16(2.0f * (qy * qz + qx * qw));
                char* p = smem + row * XSTRIDE + 600 + j * 12;
                *(uint*)p = pq.u[0];
                *(uint*)(p + 4) = pq.u[1];
                *(uint*)(p + 8) = pq.u[2];
            }
        }
        // zero pad cols 414..423 (bytes 828..847): 64 rows x 5 dwords
#pragma unroll
        for (int i = 0; i < 2; i++) {
            int id = tid + i * 256;
            if (id < 320) {
                int row = id / 5;
                int p = id - row * 5;
                *(uint*)(smem + row * XSTRIDE + 828 + p * 4) = 0u;
            }
        }
    }
    __syncthreads();  // x slab ready

    f32x4 acc[4][8];
    f32x4 zero4 = {0.0f, 0.0f, 0.0f, 0.0f};
#pragma unroll
    for (int i = 0; i < 4; i++)
#pragma unroll
        for (int j = 0; j < 8; j++) acc[i][j] = zero4;

    // ---- layer 1: h1 = relu(x @ W1 + b1), K=416 ----
    mlp_layer<13, 32, XSTRIDE>(smem + lrow * XSTRIDE + kgrp * 16,
                               (const char*)W1p + (wn << 13), laneOff, acc);
    __syncthreads();
    store_h_relu(acc, smem, b1, wn, lrow, kgrp);
    __syncthreads();

    // ---- layer 2: h2 = relu(h1 @ W2 + b2), K=512 ----
#pragma unroll
    for (int i = 0; i < 4; i++)
#pragma unroll
        for (int j = 0; j < 8; j++) acc[i][j] = zero4;
    mlp_layer<16, 32, HSTRIDE>(smem + lrow * HSTRIDE + kgrp * 16,
                               (const char*)W2p + (wn << 13), laneOff, acc);
    __syncthreads();
    store_h_relu(acc, smem, b2, wn, lrow, kgrp);
    __syncthreads();

    // ---- layer 3: delta = (h2 @ W3 + b3) * std + mean, N=120(128) ----
    // wave wn owns cols [wn*32, +32): acc 4 m-tiles x 2 n-tiles.
    f32x4 a3[4][2];
#pragma unroll
    for (int i = 0; i < 4; i++)
#pragma unroll
        for (int j = 0; j < 2; j++) a3[i][j] = zero4;
    {
        const char* Ab = smem + lrow * HSTRIDE + kgrp * 16;
        const char* Bb = (const char*)W3p;
        bf16x8 c0[2], c1[2];
#pragma unroll
        for (int j = 0; j < 2; j++)
            c0[j] = *(const bf16x8*)(Bb + ((wn * 2 + j) << 10) + laneOff);
#pragma unroll 2
        for (int ks = 0; ks < 16; ks++) {
            if (ks + 1 < 16) {
                if ((ks & 1) == 0) {
#pragma unroll
                    for (int j = 0; j < 2; j++)
                        c1[j] = *(const bf16x8*)(Bb + (((ks + 1) * 8 + wn * 2 + j) << 10) + laneOff);
                } else {
#pragma unroll
                    for (int j = 0; j < 2; j++)
                        c0[j] = *(const bf16x8*)(Bb + (((ks + 1) * 8 + wn * 2 + j) << 10) + laneOff);
                }
            }
            bf16x8 af[4];
#pragma unroll
            for (int i = 0; i < 4; i++)
                af[i] = *(const bf16x8*)(Ab + ks * 64 + i * 16 * HSTRIDE);
#pragma unroll
            for (int i = 0; i < 4; i++)
#pragma unroll
                for (int j = 0; j < 2; j++)
                    a3[i][j] = __builtin_amdgcn_mfma_f32_16x16x32_bf16(
                        af[i], (ks & 1) ? c1[j] : c0[j], a3[i][j], 0, 0, 0);
        }
    }
    __syncthreads();  // all waves done reading h2; smem free for delta

    // delta -> LDS fp32 [64 x 120]
    float* dl = (float*)smem;
#pragma unroll
    for (int j = 0; j < 2; j++) {
        int col = wn * 32 + j * 16 + lrow;
        if (col < 120) {
            float bb = b3[col], sc = dstd[col], mn = dmean[col];
#pragma unroll
            for (int i = 0; i < 4; i++) {
#pragma unroll
                for (int r = 0; r < 4; r++) {
                    int row = i * 16 + kgrp * 4 + r;
                    dl[row * 120 + col] = (a3[i][j][r] + bb) * sc + mn;
                }
            }
        }
    }
    __syncthreads();

    // ---- integrate: 64 rows x 20 bodies = 1280 items, 5 per thread ----
#pragma unroll
    for (int it = 0; it < 5; it++) {
        int idx = tid + it * 256;
        int lr = idx / 20;
        int body = idx - lr * 20;
        int rowg = blk * 64 + lr;
        const float* sb = state + (size_t)rowg * 260 + body * 13;
        const float* rq = state + (size_t)rowg * 260 + 3;  // root quat
        float qx = rq[0], qy = rq[1], qz = rq[2], qw = rq[3];
        const float* d = dl + lr * 120 + body * 6;

        float lx, ly, lz, ax, ay, az;
        quat_apply3(qx, qy, qz, qw, d[0], d[1], d[2], lx, ly, lz);
        quat_apply3(qx, qy, qz, qw, d[3], d[4], d[5], ax, ay, az);

        float vx = sb[7] + lx, vy = sb[8] + ly, vz = sb[9] + lz;
        float wx = sb[10] + ax, wy = sb[11] + ay, wz = sb[12] + az;
        float px = sb[0] + vx * DT, py = sb[1] + vy * DT, pz = sb[2] + vz * DT;

        float rx = sb[3], ry = sb[4], rz = sb[5], rw = sb[6];
        float dqx = rw * wx + (wy * rz - wz * ry);
        float dqy = rw * wy + (wz * rx - wx * rz);
        float dqz = rw * wz + (wx * ry - wy * rx);
        float dqw = -(wx * rx + wy * ry + wz * rz);
        float h = 0.5f * DT;
        float nx = rx + h * dqx, ny = ry + h * dqy, nz = rz + h * dqz,
              nw = rw + h * dqw;
        float inv = 1.0f / sqrtf(nx * nx + ny * ny + nz * nz + nw * nw);

        float* o = out + (size_t)rowg * 260 + body * 13;
        o[0] = px;
        o[1] = py;
        o[2] = pz;
        o[3] = nx * inv;
        o[4] = ny * inv;
        o[5] = nz * inv;
        o[6] = nw * inv;
        o[7] = vx;
        o[8] = vy;
        o[9] = vz;
        o[10] = wx;
        o[11] = wy;
        o[12] = wz;
    }
}

// ---------------------------------------------------------------------------
extern "C" void kernel_launch(void* const* d_in, const int* in_sizes, int n_in,
                              void* d_out, int out_size, void* d_ws,
                              size_t ws_size, hipStream_t stream) {
    const float* state = (const float*)d_in[0];
    const float* action = (const float*)d_in[1];
    const float* obs = (const float*)d_in[2];
    const float* W1 = (const float*)d_in[3];
    const float* b1 = (const float*)d_in[4];
    const float* W2 = (const float*)d_in[5];
    const float* b2 = (const float*)d_in[6];
    const float* W3 = (const float*)d_in[7];
    const float* b3 = (const float*)d_in[8];
    const float* dmean = (const float*)d_in[9];
    const float* dstd = (const float*)d_in[10];
    float* out = (float*)d_out;
    char* ws = (char*)d_ws;

    const int B = in_sizes[1] / 57;  // 32768

    __hip_bfloat16* W1p = (__hip_bfloat16*)(ws);           // 13*32 frags
    __hip_bfloat16* W2p = (__hip_bfloat16*)(ws + 425984);  // 16*32 frags
    __hip_bfloat16* W3p = (__hip_bfloat16*)(ws + 950272);  // 16*8 frags

    prep_weights<<<2112, 256, 0, stream>>>(W1, W2, W3, W1p, W2p, W3p);
    fused_mlp<<<B / 64, 256, 0, stream>>>(obs, action, W1p, b1, W2p, b2, W3p,
                                          b3, dstd, dmean, state, out);
}

// Round 5
// 165.271 us; speedup vs baseline: 1.4704x; 1.0120x over previous
//
#include <hip/hip_runtime.h>
#include <hip/hip_bf16.h>
#include <math.h>

#define DT (1.0f / 60.0f)

typedef __bf16 bf16x8 __attribute__((ext_vector_type(8)));
typedef float f32x4 __attribute__((ext_vector_type(4)));

#define XSTRIDE 848   // 424 bf16 cols: 212 dwords % 8 == 4 -> 2-way (free)
#define HSTRIDE 1040  // 520 bf16 cols: 260 dwords % 8 == 4 -> 2-way (free)

// 4-byte-aligned float4 for vectorized loads of 13-float-strided state
struct __attribute__((packed)) f4u {
    float x, y, z, w;
};

// ---------------------------------------------------------------------------
// Weight prep into MFMA-fragment-packed layout.
// frag(ks, nt) is 1KB contiguous; lane l (lrow=l&15, kgrp=l>>4) reads bytes
// [l*16, +16) = W[k = ks*32 + kgrp*8 + e][n = nt*16 + lrow], e=0..7.
// Serves as the MFMA *A* operand (m=feature in lane&15, k in kgrp*8+e).
// ---------------------------------------------------------------------------
__global__ __launch_bounds__(256) void prep_weights(
    const float* __restrict__ W1, const float* __restrict__ W2,
    const float* __restrict__ W3, __hip_bfloat16* __restrict__ W1p,
    __hip_bfloat16* __restrict__ W2p, __hip_bfloat16* __restrict__ W3p) {
    int idx = blockIdx.x * 256 + threadIdx.x;
    if (idx < 212992) {  // W1p: KS=13, NT=32 (K pad 416, N=512)
        int d = idx;
        int e = d & 7, l = (d >> 3) & 63, t = d >> 9;
        int nt = t & 31, ks = t >> 5;
        int n = nt * 16 + (l & 15);
        int k = ks * 32 + (l >> 4) * 8 + e;
        W1p[d] = __float2bfloat16(k < 414 ? W1[k * 512 + n] : 0.0f);
        return;
    }
    idx -= 212992;
    if (idx < 262144) {  // W2p: KS=16, NT=32
        int d = idx;
        int e = d & 7, l = (d >> 3) & 63, t = d >> 9;
        int nt = t & 31, ks = t >> 5;
        int n = nt * 16 + (l & 15);
        int k = ks * 32 + (l >> 4) * 8 + e;
        W2p[d] = __float2bfloat16(W2[k * 512 + n]);
        return;
    }
    idx -= 262144;
    if (idx < 65536) {  // W3p: KS=16, NT=8 (N pad 128)
        int d = idx;
        int e = d & 7, l = (d >> 3) & 63, t = d >> 9;
        int nt = t & 7, ks = t >> 3;
        int n = nt * 16 + (l & 15);
        int k = ks * 32 + (l >> 4) * 8 + e;
        W3p[d] = __float2bfloat16(n < 120 ? W3[k * 120 + n] : 0.0f);
    }
}

// ---------------------------------------------------------------------------
// K-loop, transposed operands: acc[i][j] = W_frag[j] x Act_frag[i].
// D layout: batchrow = lane&15 (+16*i), feature = kgrp*4 + reg (+16*j).
// Wave wn owns features [wn*128, +128), all 64 batch rows.
// ---------------------------------------------------------------------------
template <int KSTEPS, int NT, int ASTRIDE>
__device__ __forceinline__ void mlp_layer(const char* Abase, const char* Bbase,
                                          int laneOff, f32x4 (&acc)[4][8]) {
    bf16x8 w0[8], w1[8];
#pragma unroll
    for (int j = 0; j < 8; j++)
        w0[j] = *(const bf16x8*)(Bbase + (j << 10) + laneOff);
#pragma unroll 2
    for (int ks = 0; ks < KSTEPS; ks++) {
        if (ks + 1 < KSTEPS) {
            if ((ks & 1) == 0) {
#pragma unroll
                for (int j = 0; j < 8; j++)
                    w1[j] = *(const bf16x8*)(Bbase + (((ks + 1) * NT + j) << 10) + laneOff);
            } else {
#pragma unroll
                for (int j = 0; j < 8; j++)
                    w0[j] = *(const bf16x8*)(Bbase + (((ks + 1) * NT + j) << 10) + laneOff);
            }
        }
        bf16x8 ax[4];
#pragma unroll
        for (int i = 0; i < 4; i++)
            ax[i] = *(const bf16x8*)(Abase + ks * 64 + i * 16 * ASTRIDE);
#pragma unroll
        for (int i = 0; i < 4; i++)
#pragma unroll
            for (int j = 0; j < 8; j++)
                acc[i][j] = __builtin_amdgcn_mfma_f32_16x16x32_bf16(
                    (ks & 1) ? w1[j] : w0[j], ax[i], acc[i][j], 0, 0, 0);
    }
}

// Transposed epilogue: lane writes 4 consecutive features (8 B) per (i,j).
__device__ __forceinline__ void store_h_relu_t(const f32x4 (&acc)[4][8],
                                               char* smem, const float* bias,
                                               int wn, int lrow, int kgrp) {
#pragma unroll
    for (int j = 0; j < 8; j++) {
        int f = wn * 128 + j * 16 + kgrp * 4;
        float4 bb = *(const float4*)(bias + f);
#pragma unroll
        for (int i = 0; i < 4; i++) {
            float v0 = acc[i][j][0] + bb.x;
            float v1 = acc[i][j][1] + bb.y;
            float v2 = acc[i][j][2] + bb.z;
            float v3 = acc[i][j][3] + bb.w;
            v0 = v0 > 0.0f ? v0 : 0.0f;
            v1 = v1 > 0.0f ? v1 : 0.0f;
            v2 = v2 > 0.0f ? v2 : 0.0f;
            v3 = v3 > 0.0f ? v3 : 0.0f;
            union { __hip_bfloat162 h2[2]; uint2 u; } pk;
            pk.h2[0] = __float22bfloat162_rn(make_float2(v0, v1));
            pk.h2[1] = __float22bfloat162_rn(make_float2(v2, v3));
            *(uint2*)(smem + (i * 16 + lrow) * HSTRIDE + f * 2) = pk.u;
        }
    }
}

__device__ __forceinline__ void quat_apply3(float qx, float qy, float qz,
                                            float qw, float vx, float vy,
                                            float vz, float& ox, float& oy,
                                            float& oz) {
    float tx = 2.0f * (qy * vz - qz * vy);
    float ty = 2.0f * (qz * vx - qx * vz);
    float tz = 2.0f * (qx * vy - qy * vx);
    ox = vx + qw * tx + (qy * tz - qz * ty);
    oy = vy + qw * ty + (qz * tx - qx * tz);
    oz = vz + qw * tz + (qx * ty - qy * tx);
}

// ---------------------------------------------------------------------------
// Fused: build features + 3-layer MLP + integrate.
// 512 blocks x 256 threads (4 waves). Block = 64 batch rows in LDS.
// LDS 66560 B -> 2 blocks/CU.
// ---------------------------------------------------------------------------
__global__ __launch_bounds__(256, 2) void fused_mlp(
    const float* __restrict__ obs, const float* __restrict__ action,
    const __hip_bfloat16* __restrict__ W1p, const float* __restrict__ b1,
    const __hip_bfloat16* __restrict__ W2p, const float* __restrict__ b2,
    const __hip_bfloat16* __restrict__ W3p, const float* __restrict__ b3,
    const float* __restrict__ dstd, const float* __restrict__ dmean,
    const float* __restrict__ state, float* __restrict__ out) {
    alignas(16) __shared__ char smem[64 * HSTRIDE];  // 66560 B
    const int tid = threadIdx.x;
    const int blk = blockIdx.x;
    const int lane = tid & 63, wn = tid >> 6;
    const int lrow = lane & 15, kgrp = lane >> 4;
    const int laneOff = lane * 16;

    // ---- stage obs -> bf16 LDS (stride XSTRIDE) + fused feature build ----
    {
        const float4* og = (const float4*)obs + (size_t)blk * 64 * 75;
#pragma unroll
        for (int i = 0; i < 19; i++) {
            int f = tid + i * 256;
            if (f < 4800) {
                int row = f / 75;
                int c4 = f - row * 75;
                float4 v = og[f];
                union { __hip_bfloat162 h2[2]; uint2 u; } pk;
                pk.h2[0] = __float22bfloat162_rn(make_float2(v.x, v.y));
                pk.h2[1] = __float22bfloat162_rn(make_float2(v.z, v.w));
                *(uint2*)(smem + row * XSTRIDE + c4 * 8) = pk.u;
            }
        }
        // quat 6d features: 64 rows x 19 quats
#pragma unroll
        for (int i = 0; i < 5; i++) {
            int q = tid + i * 256;
            if (q < 1216) {
                int row = q / 19;
                int j = q - row * 19;
                const float* a = action + ((size_t)(blk * 64 + row)) * 57 + j * 3;
                float rx = a[0], ry = a[1], rz = a[2];
                float ang = sqrtf(rx * rx + ry * ry + rz * rz);
                float half = 0.5f * ang;
                float s;
                if (ang < 1e-8f)
                    s = 0.5f - ang * ang * (1.0f / 48.0f);
                else
                    s = sinf(half) / ang;
                float qx = rx * s, qy = ry * s, qz = rz * s, qw = cosf(half);
                // flip_quat_by_w dropped: R(-q) == R(q).
                union { __hip_bfloat16 h[6]; uint u[3]; } pq;
                pq.h[0] = __float2bfloat16(1.0f - 2.0f * (qy * qy + qz * qz));
                pq.h[1] = __float2bfloat16(2.0f * (qx * qy - qz * qw));
                pq.h[2] = __float2bfloat16(2.0f * (qx * qy + qz * qw));
                pq.h[3] = __float2bfloat16(1.0f - 2.0f * (qx * qx + qz * qz));
                pq.h[4] = __float2bfloat16(2.0f * (qx * qz - qy * qw));
                pq.h[5] = __float2bfloat16(2.0f * (qy * qz + qx * qw));
                char* p = smem + row * XSTRIDE + 600 + j * 12;
                *(uint*)p = pq.u[0];
                *(uint*)(p + 4) = pq.u[1];
                *(uint*)(p + 8) = pq.u[2];
            }
        }
        // zero pad cols 414..423
#pragma unroll
        for (int i = 0; i < 2; i++) {
            int id = tid + i * 256;
            if (id < 320) {
                int row = id / 5;
                int p = id - row * 5;
                *(uint*)(smem + row * XSTRIDE + 828 + p * 4) = 0u;
            }
        }
    }
    __syncthreads();  // x slab ready

    f32x4 acc[4][8];
    f32x4 zero4 = {0.0f, 0.0f, 0.0f, 0.0f};
#pragma unroll
    for (int i = 0; i < 4; i++)
#pragma unroll
        for (int j = 0; j < 8; j++) acc[i][j] = zero4;

    // ---- layer 1: h1 = relu(x @ W1 + b1), K=416 ----
    mlp_layer<13, 32, XSTRIDE>(smem + lrow * XSTRIDE + kgrp * 16,
                               (const char*)W1p + (wn << 13), laneOff, acc);
    __syncthreads();
    store_h_relu_t(acc, smem, b1, wn, lrow, kgrp);
    __syncthreads();

    // ---- layer 2: h2 = relu(h1 @ W2 + b2), K=512 ----
#pragma unroll
    for (int i = 0; i < 4; i++)
#pragma unroll
        for (int j = 0; j < 8; j++) acc[i][j] = zero4;
    mlp_layer<16, 32, HSTRIDE>(smem + lrow * HSTRIDE + kgrp * 16,
                               (const char*)W2p + (wn << 13), laneOff, acc);
    __syncthreads();
    store_h_relu_t(acc, smem, b2, wn, lrow, kgrp);
    __syncthreads();

    // ---- prefetch integrate state into registers (hidden under layer 3) ---
    f4u ps0[5], ps1[5], ps2[5], prq[5];
    float ps12[5];
#pragma unroll
    for (int it = 0; it < 5; it++) {
        int idx = tid + it * 256;
        int lr = idx / 20;
        int body = idx - lr * 20;
        const float* sb = state + ((size_t)(blk * 64 + lr)) * 260 + body * 13;
        const float* rq = state + ((size_t)(blk * 64 + lr)) * 260 + 3;
        ps0[it] = *(const f4u*)sb;
        ps1[it] = *(const f4u*)(sb + 4);
        ps2[it] = *(const f4u*)(sb + 8);
        ps12[it] = sb[12];
        prq[it] = *(const f4u*)rq;
    }

    // ---- layer 3: delta = (h2 @ W3 + b3) * std + mean, N=120(128) ----
    // wave wn owns features [wn*32, +32): a3[bt 0..3][ft 0..1]
    f32x4 a3[4][2];
#pragma unroll
    for (int i = 0; i < 4; i++)
#pragma unroll
        for (int j = 0; j < 2; j++) a3[i][j] = zero4;
    {
        const char* Ab = smem + lrow * HSTRIDE + kgrp * 16;
        const char* Bb = (const char*)W3p;
        bf16x8 c0[2], c1[2];
#pragma unroll
        for (int j = 0; j < 2; j++)
            c0[j] = *(const bf16x8*)(Bb + ((wn * 2 + j) << 10) + laneOff);
#pragma unroll 2
        for (int ks = 0; ks < 16; ks++) {
            if (ks + 1 < 16) {
                if ((ks & 1) == 0) {
#pragma unroll
                    for (int j = 0; j < 2; j++)
                        c1[j] = *(const bf16x8*)(Bb + (((ks + 1) * 8 + wn * 2 + j) << 10) + laneOff);
                } else {
#pragma unroll
                    for (int j = 0; j < 2; j++)
                        c0[j] = *(const bf16x8*)(Bb + (((ks + 1) * 8 + wn * 2 + j) << 10) + laneOff);
                }
            }
            bf16x8 ax[4];
#pragma unroll
            for (int i = 0; i < 4; i++)
                ax[i] = *(const bf16x8*)(Ab + ks * 64 + i * 16 * HSTRIDE);
#pragma unroll
            for (int i = 0; i < 4; i++)
#pragma unroll
                for (int j = 0; j < 2; j++)
                    a3[i][j] = __builtin_amdgcn_mfma_f32_16x16x32_bf16(
                        (ks & 1) ? c1[j] : c0[j], ax[i], a3[i][j], 0, 0, 0);
        }
    }
    __syncthreads();  // all waves done reading h2; smem free for delta

    // delta -> LDS fp32 [64 x 120]: lane writes float4 (4 features) per bt
    float* dl = (float*)smem;
#pragma unroll
    for (int j = 0; j < 2; j++) {
        int f = wn * 32 + j * 16 + kgrp * 4;
        if (f < 120) {
            float4 bb = *(const float4*)(b3 + f);
            float4 sc = *(const float4*)(dstd + f);
            float4 mn = *(const float4*)(dmean + f);
#pragma unroll
            for (int i = 0; i < 4; i++) {
                int row = i * 16 + lrow;
                float4 dv;
                dv.x = (a3[i][j][0] + bb.x) * sc.x + mn.x;
                dv.y = (a3[i][j][1] + bb.y) * sc.y + mn.y;
                dv.z = (a3[i][j][2] + bb.z) * sc.z + mn.z;
                dv.w = (a3[i][j][3] + bb.w) * sc.w + mn.w;
                *(float4*)(dl + row * 120 + f) = dv;
            }
        }
    }
    __syncthreads();

    // ---- integrate: 64 rows x 20 bodies = 1280 items, 5 per thread ----
#pragma unroll
    for (int it = 0; it < 5; it++) {
        int idx = tid + it * 256;
        int lr = idx / 20;
        int body = idx - lr * 20;
        int rowg = blk * 64 + lr;
        float qx = prq[it].x, qy = prq[it].y, qz = prq[it].z, qw = prq[it].w;
        const float* d = dl + lr * 120 + body * 6;

        float lx, ly, lz, ax, ay, az;
        quat_apply3(qx, qy, qz, qw, d[0], d[1], d[2], lx, ly, lz);
        quat_apply3(qx, qy, qz, qw, d[3], d[4], d[5], ax, ay, az);

        float vx = ps1[it].w + lx, vy = ps2[it].x + ly, vz = ps2[it].y + lz;
        float wx = ps2[it].z + ax, wy = ps2[it].w + ay, wz = ps12[it] + az;
        float px = ps0[it].x + vx * DT, py = ps0[it].y + vy * DT,
              pz = ps0[it].z + vz * DT;

        float rx = ps0[it].w, ry = ps1[it].x, rz = ps1[it].y, rw = ps1[it].z;
        float dqx = rw * wx + (wy * rz - wz * ry);
        float dqy = rw * wy + (wz * rx - wx * rz);
        float dqz = rw * wz + (wx * ry - wy * rx);
        float dqw = -(wx * rx + wy * ry + wz * rz);
        float h = 0.5f * DT;
        float nx = rx + h * dqx, ny = ry + h * dqy, nz = rz + h * dqz,
              nw = rw + h * dqw;
        float inv = 1.0f / sqrtf(nx * nx + ny * ny + nz * nz + nw * nw);

        float* o = out + (size_t)rowg * 260 + body * 13;
        o[0] = px;
        o[1] = py;
        o[2] = pz;
        o[3] = nx * inv;
        o[4] = ny * inv;
        o[5] = nz * inv;
        o[6] = nw * inv;
        o[7] = vx;
        o[8] = vy;
        o[9] = vz;
        o[10] = wx;
        o[11] = wy;
        o[12] = wz;
    }
}

// ---------------------------------------------------------------------------
extern "C" void kernel_launch(void* const* d_in, const int* in_sizes, int n_in,
                              void* d_out, int out_size, void* d_ws,
                              size_t ws_size, hipStream_t stream) {
    const float* state = (const float*)d_in[0];
    const float* action = (const float*)d_in[1];
    const float* obs = (const float*)d_in[2];
    const float* W1 = (const float*)d_in[3];
    const float* b1 = (const float*)d_in[4];
    const float* W2 = (const float*)d_in[5];
    const float* b2 = (const float*)d_in[6];
    const float* W3 = (const float*)d_in[7];
    const float* b3 = (const float*)d_in[8];
    const float* dmean = (const float*)d_in[9];
    const float* dstd = (const float*)d_in[10];
    float* out = (float*)d_out;
    char* ws = (char*)d_ws;

    const int B = in_sizes[1] / 57;  // 32768

    __hip_bfloat16* W1p = (__hip_bfloat16*)(ws);           // 13*32 frags
    __hip_bfloat16* W2p = (__hip_bfloat16*)(ws + 425984);  // 16*32 frags
    __hip_bfloat16* W3p = (__hip_bfloat16*)(ws + 950272);  // 16*8 frags

    prep_weights<<<2112, 256, 0, stream>>>(W1, W2, W3, W1p, W2p, W3p);
    fused_mlp<<<B / 64, 256, 0, stream>>>(obs, action, W1p, b1, W2p, b2, W3p,
                                          b3, dstd, dmean, state, out);
}